// Round 6
// baseline (293.817 us; speedup 1.0000x reference)
//
#include <hip/hip_runtime.h>
#include <math.h>

#define S_LEN 4096
#define F_DIM 512
#define NSPLIT 8
#define KSPLIT (S_LEN / NSPLIT)
#define FIXED_M 4.0f

typedef __attribute__((ext_vector_type(8))) short bf16x8;
typedef __attribute__((ext_vector_type(4))) float f32x4;
typedef __attribute__((ext_vector_type(16))) float f32x16;

__device__ __forceinline__ unsigned short f2bf(float x) {
    union { float f; unsigned u; } v; v.f = x;
    unsigned r = v.u + 0x7fffu + ((v.u >> 16) & 1u);
    return (unsigned short)(r >> 16);
}
__device__ __forceinline__ float bf2f(unsigned short b) {
    union { unsigned u; float f; } v; v.u = ((unsigned)b) << 16;
    return v.f;
}
__device__ __forceinline__ void load_lds16(const void* g, void* l) {
    __builtin_amdgcn_global_load_lds(
        (const __attribute__((address_space(1))) unsigned int*)g,
        (__attribute__((address_space(3))) unsigned int*)l, 16, 0, 0);
}

// ---------------- fused fp32 -> bf16 casts ----------------
struct CastArgs {
    const float* src[7];
    unsigned short* dst[7];
    int n4[7];
};
__global__ void cast_all(CastArgs a) {
    int r = blockIdx.y;
    int i = blockIdx.x * blockDim.x + threadIdx.x;
    if (i >= a.n4[r]) return;
    float4 v = ((const float4*)a.src[r])[i];
    ushort4 o;
    o.x = f2bf(v.x); o.y = f2bf(v.y); o.z = f2bf(v.z); o.w = f2bf(v.w);
    ((ushort4*)a.dst[r])[i] = o;
}

// ---------------- 128x128 GEMM, frag-packed LDS staging ----------------
// out modes: row-major bf16, row-major f32, kkf (QK B-frag pack), vvf (PV B-frag pack).
// kkf[jt][kc][lane(h,n5)][e]  : element kk[jt*32+n5][kc*16+h*8+e]
// vvf[jt][nt][c][lane(h,n5)][e]: element vv[jt*32+c*16+h*8+e][nt*32+n5]
struct GemmDesc {
    const unsigned short* X;
    const unsigned short* W;
    const float* bias;
    unsigned short* out_bf;
    float* out_f32;
    unsigned short* out_kkf;
    unsigned short* out_vvf;
    int relu;
};
struct GemmArgs { GemmDesc d[5]; };

__launch_bounds__(256, 2)
__global__ void gemm128(GemmArgs args) {
    __shared__ __align__(16) unsigned short As[8 * 512];  // 8 A-frags (16 rows x 32 k each)
    __shared__ __align__(16) unsigned short Bs[8 * 512];
    const GemmDesc d = args.d[blockIdx.y >> 2];
    const int n0 = (blockIdx.y & 3) * 128;
    const int m0 = blockIdx.x * 128;
    const int tid = threadIdx.x;
    const int w = tid >> 6, l = tid & 63, quad = l >> 4, ln = l & 15;
    const int wr = w >> 1, wc = w & 1;

    f32x4 acc[4][4];
    f32x4 zero4 = {0.f, 0.f, 0.f, 0.f};
#pragma unroll
    for (int i = 0; i < 4; ++i)
#pragma unroll
        for (int j = 0; j < 4; ++j) acc[i][j] = zero4;

    for (int k0 = 0; k0 < F_DIM; k0 += 32) {
        __syncthreads();
        // frag-packed DMA: frag c covers rows [c*16, c*16+16) x k [k0, k0+32)
        // lane l -> global row (base + c*16 + ln), cols k0 + quad*8 .. +8 (16B)
#pragma unroll
        for (int i = 0; i < 2; ++i) {
            int c = w * 2 + i;
            load_lds16(d.X + (size_t)(m0 + c * 16 + ln) * F_DIM + k0 + quad * 8, &As[c * 512]);
            load_lds16(d.W + (size_t)(n0 + c * 16 + ln) * F_DIM + k0 + quad * 8, &Bs[c * 512]);
        }
        __syncthreads();
        bf16x8 af[4], bfr[4];
#pragma unroll
        for (int mt = 0; mt < 4; ++mt)
            af[mt] = *(const bf16x8*)&As[(wr * 4 + mt) * 512 + l * 8];  // stride 4dw: conflict-free
#pragma unroll
        for (int nt = 0; nt < 4; ++nt)
            bfr[nt] = *(const bf16x8*)&Bs[(wc * 4 + nt) * 512 + l * 8];
#pragma unroll
        for (int mt = 0; mt < 4; ++mt)
#pragma unroll
            for (int nt = 0; nt < 4; ++nt)
                acc[mt][nt] = __builtin_amdgcn_mfma_f32_16x16x32_bf16(af[mt], bfr[nt], acc[mt][nt], 0, 0, 0);
    }

#pragma unroll
    for (int mt = 0; mt < 4; ++mt)
#pragma unroll
        for (int nt = 0; nt < 4; ++nt)
#pragma unroll
            for (int r = 0; r < 4; ++r) {
                int row = m0 + wr * 64 + mt * 16 + quad * 4 + r;
                int col = n0 + wc * 64 + nt * 16 + ln;
                float vv = acc[mt][nt][r] + d.bias[col];
                if (d.relu) vv = fmaxf(vv, 0.f);
                unsigned short bv = f2bf(vv);
                if (d.out_bf)  d.out_bf[(size_t)row * F_DIM + col] = bv;
                if (d.out_f32) d.out_f32[(size_t)row * F_DIM + col] = vv;
                if (d.out_kkf) {
                    int jt = row >> 5, rn5 = row & 31;
                    int kc = col >> 4, hh = (col >> 3) & 1, e = col & 7;
                    d.out_kkf[(size_t)(jt * 32 + kc) * 512 + hh * 256 + rn5 * 8 + e] = bv;
                }
                if (d.out_vvf) {
                    int jt = row >> 5, c = (row >> 4) & 1, hh = (row >> 3) & 1, e = row & 7;
                    int nt2 = col >> 5, cn5 = col & 31;
                    d.out_vvf[((size_t)(jt * 16 + nt2) * 2 + c) * 512 + hh * 256 + cn5 * 8 + e] = bv;
                }
            }
}

// ---------------- flash attention v3 ----------------
// Block = 4 waves sharing 32 Q rows (Qs in LDS, frag-packed). Tile = 128 j.
// Wave w: QK on j-subtile [32w..32w+32) (no redundancy), PV on F-quarter [128w..+128).
// B-operands stream fragment-packed from global (kkf/vvf) -> 1KB coalesced loads, L2-hot.
// Regs ~150 -> 2 waves/SIMD, 8 waves/CU. 2 barriers/tile. Fixed-max softmax.
__launch_bounds__(256, 2)
__global__ void flash_attn(const unsigned short* __restrict__ qq,
                           const unsigned short* __restrict__ kkf,
                           const unsigned short* __restrict__ vvf,
                           unsigned short* __restrict__ O_part,  // [NSPLIT][S][F] bf16
                           float* __restrict__ l_part) {         // [NSPLIT][S]
    __shared__ __align__(16) unsigned short Qs[32 * 512];  // 32 A-frags (32 KB)
    __shared__ __align__(16) unsigned short Ps[32][136];   // 8.7 KB, stride 68dw = 4 mod 32
    __shared__ float lred[4][34];
    const float scale = 0.04415108f;  // 1/sqrt(513)
    const int tid = threadIdx.x;
    const int w = tid >> 6, l = tid & 63, n5 = l & 31, h = l >> 5;
    const int split = blockIdx.x;
    const int m0 = blockIdx.y * 32;
    const int j_begin = split * KSPLIT;

    // stage Q (32 rows x 512) as 32 frag-packed A-frags; frag kc: lane(h,n5) <-
    // qq[m0+n5][kc*16 + h*8 .. +8]
#pragma unroll
    for (int i = 0; i < 8; ++i) {
        int kc = w * 8 + i;
        load_lds16(qq + (size_t)(m0 + n5) * F_DIM + kc * 16 + h * 8, &Qs[kc * 512]);
    }
    __syncthreads();

    f32x16 o[4];
#pragma unroll
    for (int i = 0; i < 4; ++i)
#pragma unroll
        for (int r = 0; r < 16; ++r) o[i][r] = 0.f;
    float lacc[16];
#pragma unroll
    for (int r = 0; r < 16; ++r) lacc[r] = 0.f;

    for (int t = 0; t < KSPLIT / 128; ++t) {
        const int j0 = j_begin + t * 128;
        // ---- QK: S(32 x 32) for this wave's j-subtile ----
        f32x16 s0, s1;
#pragma unroll
        for (int r = 0; r < 16; ++r) { s0[r] = 0.f; s1[r] = 0.f; }
        const unsigned short* kb = kkf + ((size_t)((j0 >> 5) + w) * 32) * 512 + l * 8;
#pragma unroll
        for (int kc = 0; kc < 32; kc += 2) {
            bf16x8 a0 = *(const bf16x8*)&Qs[kc * 512 + l * 8];
            bf16x8 a1 = *(const bf16x8*)&Qs[(kc + 1) * 512 + l * 8];
            bf16x8 b0 = *(const bf16x8*)(kb + (size_t)kc * 512);
            bf16x8 b1 = *(const bf16x8*)(kb + (size_t)(kc + 1) * 512);
            s0 = __builtin_amdgcn_mfma_f32_32x32x16_bf16(a0, b0, s0, 0, 0, 0);
            s1 = __builtin_amdgcn_mfma_f32_32x32x16_bf16(a1, b1, s1, 0, 0, 0);
        }
        // ---- softmax (fixed max) + P to LDS (C -> A transform) ----
#pragma unroll
        for (int r = 0; r < 16; ++r) {
            float p = __expf((s0[r] + s1[r]) * scale - FIXED_M);
            lacc[r] += p;
            int row = (r & 3) + 8 * (r >> 2) + 4 * h;
            Ps[row][w * 32 + n5] = f2bf(p);
        }
        __syncthreads();  // full P(32x128) visible
        // ---- PV: O quarter += P(32x128) @ V(128 x 128cols) ----
        const unsigned short* vb = vvf + ((size_t)(j0 >> 5) * 16 + w * 4) * 1024 + l * 8;
#pragma unroll
        for (int cp = 0; cp < 8; ++cp) {
            bf16x8 pa = *(const bf16x8*)&Ps[n5][cp * 16 + h * 8];
            int dj = cp >> 1, c = cp & 1;
#pragma unroll
            for (int nt = 0; nt < 4; ++nt) {
                bf16x8 b = *(const bf16x8*)(vb + (size_t)dj * 16384 + (size_t)nt * 1024 + c * 512);
                o[nt] = __builtin_amdgcn_mfma_f32_32x32x16_bf16(pa, b, o[nt], 0, 0, 0);
            }
        }
        __syncthreads();  // Ps reads done before next tile overwrites
    }

    // ---- epilogue: O_part + l_part ----
    unsigned short* Op = O_part + ((size_t)split * S_LEN + m0) * F_DIM;
#pragma unroll
    for (int nt = 0; nt < 4; ++nt)
#pragma unroll
        for (int r = 0; r < 16; ++r) {
            int row = (r & 3) + 8 * (r >> 2) + 4 * h;
            Op[(size_t)row * F_DIM + (w * 4 + nt) * 32 + n5] = f2bf(o[nt][r]);
        }
    // row-sum of this wave's j-range contributions
#pragma unroll
    for (int r = 0; r < 16; ++r) {
        float v = lacc[r];
#pragma unroll
        for (int off = 16; off >= 1; off >>= 1) v += __shfl_xor(v, off);
        if (n5 == 0) {
            int row = (r & 3) + 8 * (r >> 2) + 4 * h;
            lred[w][row] = v;
        }
    }
    __syncthreads();
    if (w == 0 && l < 32)
        l_part[(size_t)split * S_LEN + m0 + l] =
            lred[0][l] + lred[1][l] + lred[2][l] + lred[3][l];
}

// ---------------- combine: fused q_att dot + split-sum + elementwise fusion ----------------
__global__ void combine_kernel(const unsigned short* __restrict__ O_part,
                               const float* __restrict__ l_part,
                               const unsigned short* __restrict__ qq,
                               const unsigned short* __restrict__ qk,
                               const unsigned short* __restrict__ qv,
                               unsigned short* __restrict__ res_bf) {
    const float scale = 0.04415108f;
    int row = blockIdx.x;
    int t = threadIdx.x;  // 128 threads = 2 waves
    int wv = t >> 6, l = t & 63;
    __shared__ float wsum[2];

    ushort4 a = *(const ushort4*)(qq + (size_t)row * F_DIM + t * 4);
    ushort4 b = *(const ushort4*)(qk + (size_t)row * F_DIM + t * 4);
    float part = bf2f(a.x) * bf2f(b.x) + bf2f(a.y) * bf2f(b.y) +
                 bf2f(a.z) * bf2f(b.z) + bf2f(a.w) * bf2f(b.w);
#pragma unroll
    for (int off = 32; off >= 1; off >>= 1) part += __shfl_xor(part, off);
    if (l == 0) wsum[wv] = part;
    __syncthreads();
    float qa = wsum[0] + wsum[1];

    float denom = __expf(qa * scale - FIXED_M);  // extra column: denominator only
#pragma unroll
    for (int i = 0; i < NSPLIT; ++i) denom += l_part[(size_t)i * S_LEN + row];
    float inv = 1.f / denom;

    for (int f = t; f < F_DIM; f += 128) {
        float acc = 0.f;
#pragma unroll
        for (int i = 0; i < NSPLIT; ++i)
            acc += bf2f(O_part[((size_t)i * S_LEN + row) * F_DIM + f]);
        float r = bf2f(qv[(size_t)row * F_DIM + f]) * qa + acc * inv;
        res_bf[(size_t)row * F_DIM + f] = f2bf(r);
    }
}

extern "C" void kernel_launch(void* const* d_in, const int* in_sizes, int n_in,
                              void* d_out, int out_size, void* d_ws, size_t ws_size,
                              hipStream_t stream) {
    const float* q  = (const float*)d_in[0];
    const float* k  = (const float*)d_in[1];
    const float* v  = (const float*)d_in[2];
    const float* Wq = (const float*)d_in[3];
    const float* bq = (const float*)d_in[4];
    const float* Wk = (const float*)d_in[5];
    const float* bk = (const float*)d_in[6];
    const float* Wv = (const float*)d_in[7];
    const float* bv = (const float*)d_in[8];
    const float* Wo = (const float*)d_in[9];
    const float* bo = (const float*)d_in[10];
    float* out = (float*)d_out;

    char* p = (char*)d_ws;
    auto alloc = [&](size_t bytes) -> char* {
        char* r = p; p += (bytes + 255) & ~(size_t)255; return r;
    };
    const size_t SF = (size_t)S_LEN * F_DIM;
    unsigned short* q_bf  = (unsigned short*)alloc(SF * 2);
    unsigned short* k_bf  = (unsigned short*)alloc(SF * 2);
    unsigned short* v_bf  = (unsigned short*)alloc(SF * 2);
    unsigned short* qq_bf = (unsigned short*)alloc(SF * 2);
    unsigned short* kkf   = (unsigned short*)alloc(SF * 2);
    unsigned short* vvf   = (unsigned short*)alloc(SF * 2);
    unsigned short* qk_bf = (unsigned short*)alloc(SF * 2);
    unsigned short* qv_bf = (unsigned short*)alloc(SF * 2);
    unsigned short* res_bf = (unsigned short*)alloc(SF * 2);
    unsigned short* wq_bf = (unsigned short*)alloc((size_t)F_DIM * F_DIM * 2);
    unsigned short* wk_bf = (unsigned short*)alloc((size_t)F_DIM * F_DIM * 2);
    unsigned short* wv_bf = (unsigned short*)alloc((size_t)F_DIM * F_DIM * 2);
    unsigned short* wo_bf = (unsigned short*)alloc((size_t)F_DIM * F_DIM * 2);
    float* l_part = (float*)alloc((size_t)NSPLIT * S_LEN * 4);
    unsigned short* O_part = (unsigned short*)alloc((size_t)NSPLIT * SF * 2);

    CastArgs ca;
    ca.src[0] = q;  ca.dst[0] = q_bf;  ca.n4[0] = (int)(SF / 4);
    ca.src[1] = k;  ca.dst[1] = k_bf;  ca.n4[1] = (int)(SF / 4);
    ca.src[2] = v;  ca.dst[2] = v_bf;  ca.n4[2] = (int)(SF / 4);
    ca.src[3] = Wq; ca.dst[3] = wq_bf; ca.n4[3] = F_DIM * F_DIM / 4;
    ca.src[4] = Wk; ca.dst[4] = wk_bf; ca.n4[4] = F_DIM * F_DIM / 4;
    ca.src[5] = Wv; ca.dst[5] = wv_bf; ca.n4[5] = F_DIM * F_DIM / 4;
    ca.src[6] = Wo; ca.dst[6] = wo_bf; ca.n4[6] = F_DIM * F_DIM / 4;
    cast_all<<<dim3((unsigned)(SF / 4 / 256), 7), 256, 0, stream>>>(ca);

    GemmArgs ga;
    ga.d[0] = { q_bf, wq_bf, bq, qq_bf, nullptr, nullptr, nullptr, 1 };
    ga.d[1] = { k_bf, wk_bf, bk, nullptr, nullptr, kkf, nullptr, 1 };  // K -> frag pack
    ga.d[2] = { v_bf, wv_bf, bv, nullptr, nullptr, nullptr, vvf, 1 }; // V -> frag pack
    ga.d[3] = { q_bf, wk_bf, bk, qk_bf, nullptr, nullptr, nullptr, 0 };
    ga.d[4] = { q_bf, wv_bf, bv, qv_bf, nullptr, nullptr, nullptr, 0 };
    gemm128<<<dim3(S_LEN / 128, 20), 256, 0, stream>>>(ga);

    // grid: split fastest -> linear id mod 8 == split -> XCD i serves only split i's K/V
    flash_attn<<<dim3(NSPLIT, S_LEN / 32), 256, 0, stream>>>(qq_bf, kkf, vvf,
                                                             O_part, l_part);

    combine_kernel<<<S_LEN, 128, 0, stream>>>(O_part, l_part, qq_bf, qk_bf, qv_bf, res_bf);

    GemmArgs ga2{};
    ga2.d[0] = { res_bf, wo_bf, bo, nullptr, out, nullptr, nullptr, 1 };
    gemm128<<<dim3(S_LEN / 128, 4), 256, 0, stream>>>(ga2);
}

// Round 7
// 280.691 us; speedup vs baseline: 1.0468x; 1.0468x over previous
//
#include <hip/hip_runtime.h>
#include <math.h>

#define S_LEN 4096
#define F_DIM 512
#define NSPLIT 8
#define KSPLIT (S_LEN / NSPLIT)
#define FIXED_M 4.0f

typedef __attribute__((ext_vector_type(8))) short bf16x8;
typedef __attribute__((ext_vector_type(4))) float f32x4;
typedef __attribute__((ext_vector_type(16))) float f32x16;

__device__ __forceinline__ unsigned short f2bf(float x) {
    union { float f; unsigned u; } v; v.f = x;
    unsigned r = v.u + 0x7fffu + ((v.u >> 16) & 1u);
    return (unsigned short)(r >> 16);
}
__device__ __forceinline__ float bf2f(unsigned short b) {
    union { unsigned u; float f; } v; v.u = ((unsigned)b) << 16;
    return v.f;
}
__device__ __forceinline__ void load_lds16(const void* g, void* l) {
    __builtin_amdgcn_global_load_lds(
        (const __attribute__((address_space(1))) unsigned int*)g,
        (__attribute__((address_space(3))) unsigned int*)l, 16, 0, 0);
}

// ---------------- fused fp32 -> bf16 casts ----------------
struct CastArgs {
    const float* src[7];
    unsigned short* dst[7];
    int n4[7];
};
__global__ void cast_all(CastArgs a) {
    int r = blockIdx.y;
    int i = blockIdx.x * blockDim.x + threadIdx.x;
    if (i >= a.n4[r]) return;
    float4 v = ((const float4*)a.src[r])[i];
    ushort4 o;
    o.x = f2bf(v.x); o.y = f2bf(v.y); o.z = f2bf(v.z); o.w = f2bf(v.w);
    ((ushort4*)a.dst[r])[i] = o;
}

// ---------------- 128x128 GEMM, frag-packed LDS staging (coalesced outputs only) ----------------
struct GemmDesc {
    const unsigned short* X;
    const unsigned short* W;
    const float* bias;
    unsigned short* out_bf;
    float* out_f32;
    int relu;
};
struct GemmArgs { GemmDesc d[5]; };

__launch_bounds__(256, 2)
__global__ void gemm128(GemmArgs args) {
    __shared__ __align__(16) unsigned short As[8 * 512];
    __shared__ __align__(16) unsigned short Bs[8 * 512];
    const GemmDesc d = args.d[blockIdx.y >> 2];
    const int n0 = (blockIdx.y & 3) * 128;
    const int m0 = blockIdx.x * 128;
    const int tid = threadIdx.x;
    const int w = tid >> 6, l = tid & 63, quad = l >> 4, ln = l & 15;
    const int wr = w >> 1, wc = w & 1;

    f32x4 acc[4][4];
    f32x4 zero4 = {0.f, 0.f, 0.f, 0.f};
#pragma unroll
    for (int i = 0; i < 4; ++i)
#pragma unroll
        for (int j = 0; j < 4; ++j) acc[i][j] = zero4;

    for (int k0 = 0; k0 < F_DIM; k0 += 32) {
        __syncthreads();
#pragma unroll
        for (int i = 0; i < 2; ++i) {
            int c = w * 2 + i;
            load_lds16(d.X + (size_t)(m0 + c * 16 + ln) * F_DIM + k0 + quad * 8, &As[c * 512]);
            load_lds16(d.W + (size_t)(n0 + c * 16 + ln) * F_DIM + k0 + quad * 8, &Bs[c * 512]);
        }
        __syncthreads();
        bf16x8 af[4], bfr[4];
#pragma unroll
        for (int mt = 0; mt < 4; ++mt)
            af[mt] = *(const bf16x8*)&As[(wr * 4 + mt) * 512 + l * 8];
#pragma unroll
        for (int nt = 0; nt < 4; ++nt)
            bfr[nt] = *(const bf16x8*)&Bs[(wc * 4 + nt) * 512 + l * 8];
#pragma unroll
        for (int mt = 0; mt < 4; ++mt)
#pragma unroll
            for (int nt = 0; nt < 4; ++nt)
                acc[mt][nt] = __builtin_amdgcn_mfma_f32_16x16x32_bf16(af[mt], bfr[nt], acc[mt][nt], 0, 0, 0);
    }

#pragma unroll
    for (int mt = 0; mt < 4; ++mt)
#pragma unroll
        for (int nt = 0; nt < 4; ++nt)
#pragma unroll
            for (int r = 0; r < 4; ++r) {
                int row = m0 + wr * 64 + mt * 16 + quad * 4 + r;
                int col = n0 + wc * 64 + nt * 16 + ln;
                float vv = acc[mt][nt][r] + d.bias[col];
                if (d.relu) vv = fmaxf(vv, 0.f);
                if (d.out_bf)  d.out_bf[(size_t)row * F_DIM + col] = f2bf(vv);
                if (d.out_f32) d.out_f32[(size_t)row * F_DIM + col] = vv;
            }
}

// ---------------- frag-pack kk,vv (row-major) -> kkf,vvf (MFMA B-operand streams) ----------------
// kkf[jt][kc][h][n5][e] = kk[jt*32+n5][kc*16+h*8+e]
// vvf[jt][nt][c][h][n5][e] = vv[jt*32 + c*16+h*8+e][nt*32+n5]
__global__ void fragpack(const unsigned short* __restrict__ kk,
                         const unsigned short* __restrict__ vv,
                         unsigned short* __restrict__ kkf,
                         unsigned short* __restrict__ vvf) {
    __shared__ __align__(16) unsigned short tile[32][520];
    const int jt = blockIdx.x;
    const int which = blockIdx.y;
    const unsigned short* src = which ? vv : kk;
    const int tid = threadIdx.x;
#pragma unroll
    for (int it = 0; it < 8; ++it) {
        int u = it * 256 + tid;
        int r = u >> 6, c = (u & 63) * 8;
        *(uint4*)&tile[r][c] = *(const uint4*)(src + (size_t)(jt * 32 + r) * F_DIM + c);
    }
    __syncthreads();
    if (which == 0) {
        unsigned short* dst = kkf + (size_t)jt * 16384;
#pragma unroll
        for (int it = 0; it < 8; ++it) {
            int u = it * 256 + tid;  // u = kc*64 + h*32 + n5
            int n5 = u & 31, h = (u >> 5) & 1, kc = u >> 6;
            unsigned short tmp[8];
#pragma unroll
            for (int e = 0; e < 8; ++e) tmp[e] = tile[n5][kc * 16 + h * 8 + e];
            *(uint4*)(dst + (size_t)u * 8) = *(uint4*)tmp;
        }
    } else {
        unsigned short* dst = vvf + (size_t)jt * 16384;
#pragma unroll
        for (int it = 0; it < 8; ++it) {
            int u = it * 256 + tid;  // u = nt*128 + c*64 + h*32 + n5
            int n5 = u & 31, h = (u >> 5) & 1, c = (u >> 6) & 1, nt = u >> 7;
            unsigned short tmp[8];
#pragma unroll
            for (int e = 0; e < 8; ++e) tmp[e] = tile[c * 16 + h * 8 + e][nt * 32 + n5];
            *(uint4*)(dst + (size_t)u * 8) = *(uint4*)tmp;
        }
    }
}

// ---------------- flash attention v4: batched register prefetch (vmcnt(N) pattern) ----------------
// Block = 4 waves sharing 32 Q rows (Qs LDS frag-pack). Tile = 128 j.
// Wave w: QK on j-subtile [32w,+32), PV on F-quarter [128w,+128). 8-16 loads in flight/wave.
__launch_bounds__(256, 2)
__global__ void flash_attn(const unsigned short* __restrict__ qq,
                           const unsigned short* __restrict__ kkf,
                           const unsigned short* __restrict__ vvf,
                           unsigned short* __restrict__ O_part,  // [NSPLIT][S][F] bf16
                           float* __restrict__ l_part) {         // [NSPLIT][S]
    __shared__ __align__(16) unsigned short Qs[32 * 512];  // 32 KB
    __shared__ __align__(16) unsigned short Ps[32][136];   // 8.7 KB (R6: 0 conflicts)
    __shared__ float lred[4][34];
    const float scale = 0.04415108f;  // 1/sqrt(513)
    const int tid = threadIdx.x;
    const int w = tid >> 6, l = tid & 63, n5 = l & 31, h = l >> 5;
    const int split = blockIdx.x;
    const int m0 = blockIdx.y * 32;
    const int j_begin = split * KSPLIT;

#pragma unroll
    for (int i = 0; i < 8; ++i) {
        int kc = w * 8 + i;
        load_lds16(qq + (size_t)(m0 + n5) * F_DIM + kc * 16 + h * 8, &Qs[kc * 512]);
    }
    __syncthreads();

    f32x16 o[4];
#pragma unroll
    for (int i = 0; i < 4; ++i)
#pragma unroll
        for (int r = 0; r < 16; ++r) o[i][r] = 0.f;
    float lacc[16];
#pragma unroll
    for (int r = 0; r < 16; ++r) lacc[r] = 0.f;

#define QK_STAGE(CUR, NXT, BASE, PREF)                                               \
    do {                                                                             \
        if ((PREF) >= 0) {                                                           \
            _Pragma("unroll")                                                        \
            for (int i = 0; i < 8; ++i)                                              \
                NXT[i] = *(const bf16x8*)(kb + (size_t)((PREF) + i) * 512);          \
        }                                                                            \
        _Pragma("unroll")                                                            \
        for (int i = 0; i < 8; i += 2) {                                             \
            bf16x8 a0 = *(const bf16x8*)&Qs[((BASE) + i) * 512 + l * 8];             \
            bf16x8 a1 = *(const bf16x8*)&Qs[((BASE) + i + 1) * 512 + l * 8];         \
            s0 = __builtin_amdgcn_mfma_f32_32x32x16_bf16(a0, CUR[i], s0, 0, 0, 0);   \
            s1 = __builtin_amdgcn_mfma_f32_32x32x16_bf16(a1, CUR[i + 1], s1, 0, 0, 0);\
        }                                                                            \
    } while (0)

#define PV_PREF(ARR, DJ)                                                             \
    _Pragma("unroll")                                                                \
    for (int i = 0; i < 8; ++i)                                                      \
        ARR[i] = *(const bf16x8*)(vb + (size_t)(DJ) * 16384 +                        \
                                  (size_t)(i >> 1) * 1024 + (size_t)(i & 1) * 512);

#define PV_STAGE(CUR, DJ)                                                            \
    _Pragma("unroll")                                                                \
    for (int c = 0; c < 2; ++c) {                                                    \
        bf16x8 pa = *(const bf16x8*)&Ps[n5][((DJ) * 2 + c) * 16 + h * 8];            \
        _Pragma("unroll")                                                            \
        for (int nt = 0; nt < 4; ++nt)                                               \
            o[nt] = __builtin_amdgcn_mfma_f32_32x32x16_bf16(pa, CUR[nt * 2 + c],     \
                                                            o[nt], 0, 0, 0);         \
    }

    for (int t = 0; t < KSPLIT / 128; ++t) {
        const int j0 = j_begin + t * 128;
        const unsigned short* kb = kkf + ((size_t)(j0 >> 5) + w) * 16384 + l * 8;
        const unsigned short* vb = vvf + ((size_t)(j0 >> 5) * 16 + w * 4) * 1024 + l * 8;

        // ---- QK: 4 ping-pong stages, 8-16 loads in flight ----
        f32x16 s0, s1;
#pragma unroll
        for (int r = 0; r < 16; ++r) { s0[r] = 0.f; s1[r] = 0.f; }
        bf16x8 kA[8], kB[8];
#pragma unroll
        for (int i = 0; i < 8; ++i) kA[i] = *(const bf16x8*)(kb + (size_t)i * 512);
        QK_STAGE(kA, kB, 0, 8);
        QK_STAGE(kB, kA, 8, 16);
        QK_STAGE(kA, kB, 16, 24);
        QK_STAGE(kB, kA, 24, -1);

        // ---- first PV batch issued before softmax/barrier ----
        bf16x8 vA[8], vB[8];
        PV_PREF(vA, 0);

        // ---- softmax (fixed max) + P -> LDS (C->A transform) ----
#pragma unroll
        for (int r = 0; r < 16; ++r) {
            float p = __expf((s0[r] + s1[r]) * scale - FIXED_M);
            lacc[r] += p;
            int row = (r & 3) + 8 * (r >> 2) + 4 * h;
            Ps[row][w * 32 + n5] = f2bf(p);
        }
        __syncthreads();  // full P(32x128) visible

        // ---- PV: 4 ping-pong stages over j-subtiles ----
        PV_PREF(vB, 1);
        PV_STAGE(vA, 0);
        PV_PREF(vA, 2);
        PV_STAGE(vB, 1);
        PV_PREF(vB, 3);
        PV_STAGE(vA, 2);
        PV_STAGE(vB, 3);
        __syncthreads();  // Ps reads done before next tile overwrites
    }

    // ---- epilogue ----
    unsigned short* Op = O_part + ((size_t)split * S_LEN + m0) * F_DIM;
#pragma unroll
    for (int nt = 0; nt < 4; ++nt)
#pragma unroll
        for (int r = 0; r < 16; ++r) {
            int row = (r & 3) + 8 * (r >> 2) + 4 * h;
            Op[(size_t)row * F_DIM + (w * 4 + nt) * 32 + n5] = f2bf(o[nt][r]);
        }
#pragma unroll
    for (int r = 0; r < 16; ++r) {
        float v = lacc[r];
#pragma unroll
        for (int off = 16; off >= 1; off >>= 1) v += __shfl_xor(v, off);
        if (n5 == 0) {
            int row = (r & 3) + 8 * (r >> 2) + 4 * h;
            lred[w][row] = v;
        }
    }
    __syncthreads();
    if (w == 0 && l < 32)
        l_part[(size_t)split * S_LEN + m0 + l] =
            lred[0][l] + lred[1][l] + lred[2][l] + lred[3][l];
}

// ---------------- combine: fused q_att dot + split-sum + elementwise fusion ----------------
__global__ void combine_kernel(const unsigned short* __restrict__ O_part,
                               const float* __restrict__ l_part,
                               const unsigned short* __restrict__ qq,
                               const unsigned short* __restrict__ qk,
                               const unsigned short* __restrict__ qv,
                               unsigned short* __restrict__ res_bf) {
    const float scale = 0.04415108f;
    int row = blockIdx.x;
    int t = threadIdx.x;  // 128 threads = 2 waves
    int wv = t >> 6, l = t & 63;
    __shared__ float wsum[2];

    ushort4 a = *(const ushort4*)(qq + (size_t)row * F_DIM + t * 4);
    ushort4 b = *(const ushort4*)(qk + (size_t)row * F_DIM + t * 4);
    float part = bf2f(a.x) * bf2f(b.x) + bf2f(a.y) * bf2f(b.y) +
                 bf2f(a.z) * bf2f(b.z) + bf2f(a.w) * bf2f(b.w);
#pragma unroll
    for (int off = 32; off >= 1; off >>= 1) part += __shfl_xor(part, off);
    if (l == 0) wsum[wv] = part;
    __syncthreads();
    float qa = wsum[0] + wsum[1];

    float denom = __expf(qa * scale - FIXED_M);  // extra column: denominator only
#pragma unroll
    for (int i = 0; i < NSPLIT; ++i) denom += l_part[(size_t)i * S_LEN + row];
    float inv = 1.f / denom;

    for (int f = t; f < F_DIM; f += 128) {
        float acc = 0.f;
#pragma unroll
        for (int i = 0; i < NSPLIT; ++i)
            acc += bf2f(O_part[((size_t)i * S_LEN + row) * F_DIM + f]);
        float r = bf2f(qv[(size_t)row * F_DIM + f]) * qa + acc * inv;
        res_bf[(size_t)row * F_DIM + f] = f2bf(r);
    }
}

extern "C" void kernel_launch(void* const* d_in, const int* in_sizes, int n_in,
                              void* d_out, int out_size, void* d_ws, size_t ws_size,
                              hipStream_t stream) {
    const float* q  = (const float*)d_in[0];
    const float* k  = (const float*)d_in[1];
    const float* v  = (const float*)d_in[2];
    const float* Wq = (const float*)d_in[3];
    const float* bq = (const float*)d_in[4];
    const float* Wk = (const float*)d_in[5];
    const float* bk = (const float*)d_in[6];
    const float* Wv = (const float*)d_in[7];
    const float* bv = (const float*)d_in[8];
    const float* Wo = (const float*)d_in[9];
    const float* bo = (const float*)d_in[10];
    float* out = (float*)d_out;

    char* p = (char*)d_ws;
    auto alloc = [&](size_t bytes) -> char* {
        char* r = p; p += (bytes + 255) & ~(size_t)255; return r;
    };
    const size_t SF = (size_t)S_LEN * F_DIM;
    unsigned short* q_bf  = (unsigned short*)alloc(SF * 2);
    unsigned short* k_bf  = (unsigned short*)alloc(SF * 2);
    unsigned short* v_bf  = (unsigned short*)alloc(SF * 2);
    unsigned short* qq_bf = (unsigned short*)alloc(SF * 2);
    unsigned short* kk_bf = (unsigned short*)alloc(SF * 2);
    unsigned short* vv_bf = (unsigned short*)alloc(SF * 2);
    unsigned short* kkf   = (unsigned short*)alloc(SF * 2);
    unsigned short* vvf   = (unsigned short*)alloc(SF * 2);
    unsigned short* qk_bf = (unsigned short*)alloc(SF * 2);
    unsigned short* qv_bf = (unsigned short*)alloc(SF * 2);
    unsigned short* res_bf = (unsigned short*)alloc(SF * 2);
    unsigned short* wq_bf = (unsigned short*)alloc((size_t)F_DIM * F_DIM * 2);
    unsigned short* wk_bf = (unsigned short*)alloc((size_t)F_DIM * F_DIM * 2);
    unsigned short* wv_bf = (unsigned short*)alloc((size_t)F_DIM * F_DIM * 2);
    unsigned short* wo_bf = (unsigned short*)alloc((size_t)F_DIM * F_DIM * 2);
    float* l_part = (float*)alloc((size_t)NSPLIT * S_LEN * 4);
    unsigned short* O_part = (unsigned short*)alloc((size_t)NSPLIT * SF * 2);

    CastArgs ca;
    ca.src[0] = q;  ca.dst[0] = q_bf;  ca.n4[0] = (int)(SF / 4);
    ca.src[1] = k;  ca.dst[1] = k_bf;  ca.n4[1] = (int)(SF / 4);
    ca.src[2] = v;  ca.dst[2] = v_bf;  ca.n4[2] = (int)(SF / 4);
    ca.src[3] = Wq; ca.dst[3] = wq_bf; ca.n4[3] = F_DIM * F_DIM / 4;
    ca.src[4] = Wk; ca.dst[4] = wk_bf; ca.n4[4] = F_DIM * F_DIM / 4;
    ca.src[5] = Wv; ca.dst[5] = wv_bf; ca.n4[5] = F_DIM * F_DIM / 4;
    ca.src[6] = Wo; ca.dst[6] = wo_bf; ca.n4[6] = F_DIM * F_DIM / 4;
    cast_all<<<dim3((unsigned)(SF / 4 / 256), 7), 256, 0, stream>>>(ca);

    GemmArgs ga;
    ga.d[0] = { q_bf, wq_bf, bq, qq_bf, nullptr, 1 };
    ga.d[1] = { k_bf, wk_bf, bk, kk_bf, nullptr, 1 };
    ga.d[2] = { v_bf, wv_bf, bv, vv_bf, nullptr, 1 };
    ga.d[3] = { q_bf, wk_bf, bk, qk_bf, nullptr, 0 };
    ga.d[4] = { q_bf, wv_bf, bv, qv_bf, nullptr, 0 };
    gemm128<<<dim3(S_LEN / 128, 20), 256, 0, stream>>>(ga);

    fragpack<<<dim3(S_LEN / 32, 2), 256, 0, stream>>>(kk_bf, vv_bf, kkf, vvf);

    flash_attn<<<dim3(NSPLIT, S_LEN / 32), 256, 0, stream>>>(qq_bf, kkf, vvf,
                                                             O_part, l_part);

    combine_kernel<<<S_LEN, 128, 0, stream>>>(O_part, l_part, qq_bf, qk_bf, qv_bf, res_bf);

    GemmArgs ga2{};
    ga2.d[0] = { res_bf, wo_bf, bo, nullptr, out, 1 };
    gemm128<<<dim3(S_LEN / 128, 4), 256, 0, stream>>>(ga2);
}

// Round 8
// 242.832 us; speedup vs baseline: 1.2100x; 1.1559x over previous
//
#include <hip/hip_runtime.h>
#include <math.h>

#define S_LEN 4096
#define F_DIM 512
#define PSPLIT 4
#define FIXED_M 4.0f

typedef __attribute__((ext_vector_type(8))) short bf16x8;
typedef __attribute__((ext_vector_type(4))) float f32x4;

__device__ __forceinline__ unsigned short f2bf(float x) {
    union { float f; unsigned u; } v; v.f = x;
    unsigned r = v.u + 0x7fffu + ((v.u >> 16) & 1u);
    return (unsigned short)(r >> 16);
}
__device__ __forceinline__ float bf2f(unsigned short b) {
    union { unsigned u; float f; } v; v.u = ((unsigned)b) << 16;
    return v.f;
}
__device__ __forceinline__ void load_lds16(const void* g, void* l) {
    __builtin_amdgcn_global_load_lds(
        (const __attribute__((address_space(1))) unsigned int*)g,
        (__attribute__((address_space(3))) unsigned int*)l, 16, 0, 0);
}

// ---------------- fused fp32 -> bf16 casts ----------------
struct CastArgs {
    const float* src[7];
    unsigned short* dst[7];
    int n4[7];
};
__global__ void cast_all(CastArgs a) {
    int r = blockIdx.y;
    int i = blockIdx.x * blockDim.x + threadIdx.x;
    if (i >= a.n4[r]) return;
    float4 v = ((const float4*)a.src[r])[i];
    ushort4 o;
    o.x = f2bf(v.x); o.y = f2bf(v.y); o.z = f2bf(v.z); o.w = f2bf(v.w);
    ((ushort4*)a.dst[r])[i] = o;
}

// ---------------- bf16 transpose: src [S][F] -> dst [F][S] (R2-verified) ----------------
__global__ void transpose_bf16(const unsigned short* __restrict__ src,
                               unsigned short* __restrict__ dst) {
    __shared__ __align__(16) unsigned short tile[64][72];
    const int s0 = blockIdx.x * 64, f0 = blockIdx.y * 64;
    const int tid = threadIdx.x;
#pragma unroll
    for (int it = 0; it < 2; ++it) {
        int u = it * 256 + tid;
        int r = u >> 3, c = (u & 7) * 8;
        *(uint4*)&tile[r][c] = *(const uint4*)(src + (size_t)(s0 + r) * F_DIM + f0 + c);
    }
    __syncthreads();
#pragma unroll
    for (int it = 0; it < 2; ++it) {
        int u = it * 256 + tid;
        int fl = u >> 3, sc = (u & 7) * 8;
        unsigned short tmp[8];
#pragma unroll
        for (int i = 0; i < 8; ++i) tmp[i] = tile[sc + i][fl];
        *(uint4*)(dst + (size_t)(f0 + fl) * S_LEN + s0 + sc) = *(uint4*)tmp;
    }
}

// ---------------- 128x128 GEMM core (m97 structure), bias+relu outputs ----------------
struct GemmDesc {
    const unsigned short* X;
    const unsigned short* W;
    const float* bias;
    unsigned short* out_bf;
    float* out_f32;
    int relu;
};
struct GemmArgs { GemmDesc d[5]; };

__launch_bounds__(256, 2)
__global__ void gemm128(GemmArgs args) {
    __shared__ __align__(16) unsigned short As[8 * 512];
    __shared__ __align__(16) unsigned short Bs[8 * 512];
    const GemmDesc d = args.d[blockIdx.y >> 2];
    const int n0 = (blockIdx.y & 3) * 128;
    const int m0 = blockIdx.x * 128;
    const int tid = threadIdx.x;
    const int w = tid >> 6, l = tid & 63, quad = l >> 4, ln = l & 15;
    const int wr = w >> 1, wc = w & 1;

    f32x4 acc[4][4];
    f32x4 zero4 = {0.f, 0.f, 0.f, 0.f};
#pragma unroll
    for (int i = 0; i < 4; ++i)
#pragma unroll
        for (int j = 0; j < 4; ++j) acc[i][j] = zero4;

    for (int k0 = 0; k0 < F_DIM; k0 += 32) {
        __syncthreads();
#pragma unroll
        for (int i = 0; i < 2; ++i) {
            int c = w * 2 + i;
            load_lds16(d.X + (size_t)(m0 + c * 16 + ln) * F_DIM + k0 + quad * 8, &As[c * 512]);
            load_lds16(d.W + (size_t)(n0 + c * 16 + ln) * F_DIM + k0 + quad * 8, &Bs[c * 512]);
        }
        __syncthreads();
        bf16x8 af[4], bfr[4];
#pragma unroll
        for (int mt = 0; mt < 4; ++mt)
            af[mt] = *(const bf16x8*)&As[(wr * 4 + mt) * 512 + l * 8];
#pragma unroll
        for (int nt = 0; nt < 4; ++nt)
            bfr[nt] = *(const bf16x8*)&Bs[(wc * 4 + nt) * 512 + l * 8];
#pragma unroll
        for (int mt = 0; mt < 4; ++mt)
#pragma unroll
            for (int nt = 0; nt < 4; ++nt)
                acc[mt][nt] = __builtin_amdgcn_mfma_f32_16x16x32_bf16(af[mt], bfr[nt], acc[mt][nt], 0, 0, 0);
    }

#pragma unroll
    for (int mt = 0; mt < 4; ++mt)
#pragma unroll
        for (int nt = 0; nt < 4; ++nt)
#pragma unroll
            for (int r = 0; r < 4; ++r) {
                int row = m0 + wr * 64 + mt * 16 + quad * 4 + r;
                int col = n0 + wc * 64 + nt * 16 + ln;
                float vv = acc[mt][nt][r] + d.bias[col];
                if (d.relu) vv = fmaxf(vv, 0.f);
                if (d.out_bf)  d.out_bf[(size_t)row * F_DIM + col] = f2bf(vv);
                if (d.out_f32) d.out_f32[(size_t)row * F_DIM + col] = vv;
            }
}

// ---------------- gemm_exp: P = exp(scale*(qq @ kk^T) - M), + per-block row sums ----------------
// grid (32, 32): m-block, n-block over 4096x4096. lpart[nb][row] = rowsum of this n-block.
__launch_bounds__(256, 2)
__global__ void gemm_exp(const unsigned short* __restrict__ X,   // qq [S][F]
                         const unsigned short* __restrict__ W,   // kk [S][F]
                         unsigned short* __restrict__ P,         // [S][S]
                         float* __restrict__ lpart) {            // [32][S]
    __shared__ __align__(16) unsigned short As[8 * 512];
    __shared__ __align__(16) unsigned short Bs[8 * 512];
    __shared__ float lsum[2][2][64];
    const float scale = 0.04415108f;  // 1/sqrt(513)
    const int nb = blockIdx.y;
    const int n0 = nb * 128;
    const int m0 = blockIdx.x * 128;
    const int tid = threadIdx.x;
    const int w = tid >> 6, l = tid & 63, quad = l >> 4, ln = l & 15;
    const int wr = w >> 1, wc = w & 1;

    f32x4 acc[4][4];
    f32x4 zero4 = {0.f, 0.f, 0.f, 0.f};
#pragma unroll
    for (int i = 0; i < 4; ++i)
#pragma unroll
        for (int j = 0; j < 4; ++j) acc[i][j] = zero4;

    for (int k0 = 0; k0 < F_DIM; k0 += 32) {
        __syncthreads();
#pragma unroll
        for (int i = 0; i < 2; ++i) {
            int c = w * 2 + i;
            load_lds16(X + (size_t)(m0 + c * 16 + ln) * F_DIM + k0 + quad * 8, &As[c * 512]);
            load_lds16(W + (size_t)(n0 + c * 16 + ln) * F_DIM + k0 + quad * 8, &Bs[c * 512]);
        }
        __syncthreads();
        bf16x8 af[4], bfr[4];
#pragma unroll
        for (int mt = 0; mt < 4; ++mt)
            af[mt] = *(const bf16x8*)&As[(wr * 4 + mt) * 512 + l * 8];
#pragma unroll
        for (int nt = 0; nt < 4; ++nt)
            bfr[nt] = *(const bf16x8*)&Bs[(wc * 4 + nt) * 512 + l * 8];
#pragma unroll
        for (int mt = 0; mt < 4; ++mt)
#pragma unroll
            for (int nt = 0; nt < 4; ++nt)
                acc[mt][nt] = __builtin_amdgcn_mfma_f32_16x16x32_bf16(af[mt], bfr[nt], acc[mt][nt], 0, 0, 0);
    }

    float rs[4][4];
#pragma unroll
    for (int mt = 0; mt < 4; ++mt)
#pragma unroll
        for (int r = 0; r < 4; ++r) rs[mt][r] = 0.f;

#pragma unroll
    for (int mt = 0; mt < 4; ++mt)
#pragma unroll
        for (int nt = 0; nt < 4; ++nt)
#pragma unroll
            for (int r = 0; r < 4; ++r) {
                int row = m0 + wr * 64 + mt * 16 + quad * 4 + r;
                int col = n0 + wc * 64 + nt * 16 + ln;
                float p = __expf(acc[mt][nt][r] * scale - FIXED_M);
                P[(size_t)row * S_LEN + col] = f2bf(p);
                rs[mt][r] += p;
            }
    // reduce over the 16 lanes (ln) of each quad-row group
#pragma unroll
    for (int mt = 0; mt < 4; ++mt)
#pragma unroll
        for (int r = 0; r < 4; ++r) {
            float v = rs[mt][r];
            v += __shfl_xor(v, 1);
            v += __shfl_xor(v, 2);
            v += __shfl_xor(v, 4);
            v += __shfl_xor(v, 8);
            if (ln == 0) lsum[wr][wc][mt * 16 + quad * 4 + r] = v;
        }
    __syncthreads();
    if (tid < 128)
        lpart[(size_t)nb * S_LEN + m0 + tid] =
            lsum[tid >> 6][0][tid & 63] + lsum[tid >> 6][1][tid & 63];
}

// ---------------- gemm_pv: O_p[split] = P[:, koff:koff+1024] @ vt[:, koff:koff+1024]^T ----------------
// grid (32, 16): y -> nb = y&3 (n0 = nb*128 over F), split = y>>2 (koff = split*1024).
__launch_bounds__(256, 2)
__global__ void gemm_pv(const unsigned short* __restrict__ P,   // [S][S]
                        const unsigned short* __restrict__ vt,  // [F][S]
                        float* __restrict__ O_p) {              // [PSPLIT][S][F]
    __shared__ __align__(16) unsigned short As[8 * 512];
    __shared__ __align__(16) unsigned short Bs[8 * 512];
    const int nb = blockIdx.y & 3;
    const int split = blockIdx.y >> 2;
    const int n0 = nb * 128;
    const int m0 = blockIdx.x * 128;
    const int koff = split * (S_LEN / PSPLIT);
    const int tid = threadIdx.x;
    const int w = tid >> 6, l = tid & 63, quad = l >> 4, ln = l & 15;
    const int wr = w >> 1, wc = w & 1;

    f32x4 acc[4][4];
    f32x4 zero4 = {0.f, 0.f, 0.f, 0.f};
#pragma unroll
    for (int i = 0; i < 4; ++i)
#pragma unroll
        for (int j = 0; j < 4; ++j) acc[i][j] = zero4;

    for (int k0 = koff; k0 < koff + S_LEN / PSPLIT; k0 += 32) {
        __syncthreads();
#pragma unroll
        for (int i = 0; i < 2; ++i) {
            int c = w * 2 + i;
            load_lds16(P + (size_t)(m0 + c * 16 + ln) * S_LEN + k0 + quad * 8, &As[c * 512]);
            load_lds16(vt + (size_t)(n0 + c * 16 + ln) * S_LEN + k0 + quad * 8, &Bs[c * 512]);
        }
        __syncthreads();
        bf16x8 af[4], bfr[4];
#pragma unroll
        for (int mt = 0; mt < 4; ++mt)
            af[mt] = *(const bf16x8*)&As[(wr * 4 + mt) * 512 + l * 8];
#pragma unroll
        for (int nt = 0; nt < 4; ++nt)
            bfr[nt] = *(const bf16x8*)&Bs[(wc * 4 + nt) * 512 + l * 8];
#pragma unroll
        for (int mt = 0; mt < 4; ++mt)
#pragma unroll
            for (int nt = 0; nt < 4; ++nt)
                acc[mt][nt] = __builtin_amdgcn_mfma_f32_16x16x32_bf16(af[mt], bfr[nt], acc[mt][nt], 0, 0, 0);
    }

    float* Op = O_p + (size_t)split * S_LEN * F_DIM;
#pragma unroll
    for (int mt = 0; mt < 4; ++mt)
#pragma unroll
        for (int nt = 0; nt < 4; ++nt)
#pragma unroll
            for (int r = 0; r < 4; ++r) {
                int row = m0 + wr * 64 + mt * 16 + quad * 4 + r;
                int col = n0 + wc * 64 + nt * 16 + ln;
                Op[(size_t)row * F_DIM + col] = acc[mt][nt][r];
            }
}

// ---------------- combine: denom + q_att dot + split-sum + elementwise fusion ----------------
__global__ void combine_kernel(const float* __restrict__ O_p,
                               const float* __restrict__ lpart,
                               const unsigned short* __restrict__ qq,
                               const unsigned short* __restrict__ qk,
                               const unsigned short* __restrict__ qv,
                               unsigned short* __restrict__ res_bf) {
    const float scale = 0.04415108f;
    int row = blockIdx.x;
    int t = threadIdx.x;  // 128 threads = 2 waves
    int wv = t >> 6, l = t & 63;
    __shared__ float wsum[2];

    ushort4 a = *(const ushort4*)(qq + (size_t)row * F_DIM + t * 4);
    ushort4 b = *(const ushort4*)(qk + (size_t)row * F_DIM + t * 4);
    float part = bf2f(a.x) * bf2f(b.x) + bf2f(a.y) * bf2f(b.y) +
                 bf2f(a.z) * bf2f(b.z) + bf2f(a.w) * bf2f(b.w);
#pragma unroll
    for (int off = 32; off >= 1; off >>= 1) part += __shfl_xor(part, off);
    if (l == 0) wsum[wv] = part;
    __syncthreads();
    float qa = wsum[0] + wsum[1];

    float denom = __expf(qa * scale - FIXED_M);  // extra column: denominator only
#pragma unroll
    for (int i = 0; i < 32; ++i) denom += lpart[(size_t)i * S_LEN + row];
    float inv = 1.f / denom;

    for (int f = t; f < F_DIM; f += 128) {
        float acc = 0.f;
#pragma unroll
        for (int i = 0; i < PSPLIT; ++i)
            acc += O_p[((size_t)i * S_LEN + row) * F_DIM + f];
        float r = bf2f(qv[(size_t)row * F_DIM + f]) * qa + acc * inv;
        res_bf[(size_t)row * F_DIM + f] = f2bf(r);
    }
}

extern "C" void kernel_launch(void* const* d_in, const int* in_sizes, int n_in,
                              void* d_out, int out_size, void* d_ws, size_t ws_size,
                              hipStream_t stream) {
    const float* q  = (const float*)d_in[0];
    const float* k  = (const float*)d_in[1];
    const float* v  = (const float*)d_in[2];
    const float* Wq = (const float*)d_in[3];
    const float* bq = (const float*)d_in[4];
    const float* Wk = (const float*)d_in[5];
    const float* bk = (const float*)d_in[6];
    const float* Wv = (const float*)d_in[7];
    const float* bv = (const float*)d_in[8];
    const float* Wo = (const float*)d_in[9];
    const float* bo = (const float*)d_in[10];
    float* out = (float*)d_out;

    char* p = (char*)d_ws;
    auto alloc = [&](size_t bytes) -> char* {
        char* r = p; p += (bytes + 255) & ~(size_t)255; return r;
    };
    const size_t SF = (size_t)S_LEN * F_DIM;
    unsigned short* q_bf  = (unsigned short*)alloc(SF * 2);
    unsigned short* k_bf  = (unsigned short*)alloc(SF * 2);
    unsigned short* v_bf  = (unsigned short*)alloc(SF * 2);
    unsigned short* qq_bf = (unsigned short*)alloc(SF * 2);
    unsigned short* kk_bf = (unsigned short*)alloc(SF * 2);
    unsigned short* vv_bf = (unsigned short*)alloc(SF * 2);
    unsigned short* vt_bf = (unsigned short*)alloc(SF * 2);
    unsigned short* qk_bf = (unsigned short*)alloc(SF * 2);
    unsigned short* qv_bf = (unsigned short*)alloc(SF * 2);
    unsigned short* res_bf = (unsigned short*)alloc(SF * 2);
    unsigned short* wq_bf = (unsigned short*)alloc((size_t)F_DIM * F_DIM * 2);
    unsigned short* wk_bf = (unsigned short*)alloc((size_t)F_DIM * F_DIM * 2);
    unsigned short* wv_bf = (unsigned short*)alloc((size_t)F_DIM * F_DIM * 2);
    unsigned short* wo_bf = (unsigned short*)alloc((size_t)F_DIM * F_DIM * 2);
    unsigned short* P_bf  = (unsigned short*)alloc((size_t)S_LEN * S_LEN * 2);  // 33.5 MB
    float* lpart = (float*)alloc((size_t)32 * S_LEN * 4);
    float* O_p   = (float*)alloc((size_t)PSPLIT * SF * 4);                      // 32 MB

    CastArgs ca;
    ca.src[0] = q;  ca.dst[0] = q_bf;  ca.n4[0] = (int)(SF / 4);
    ca.src[1] = k;  ca.dst[1] = k_bf;  ca.n4[1] = (int)(SF / 4);
    ca.src[2] = v;  ca.dst[2] = v_bf;  ca.n4[2] = (int)(SF / 4);
    ca.src[3] = Wq; ca.dst[3] = wq_bf; ca.n4[3] = F_DIM * F_DIM / 4;
    ca.src[4] = Wk; ca.dst[4] = wk_bf; ca.n4[4] = F_DIM * F_DIM / 4;
    ca.src[5] = Wv; ca.dst[5] = wv_bf; ca.n4[5] = F_DIM * F_DIM / 4;
    ca.src[6] = Wo; ca.dst[6] = wo_bf; ca.n4[6] = F_DIM * F_DIM / 4;
    cast_all<<<dim3((unsigned)(SF / 4 / 256), 7), 256, 0, stream>>>(ca);

    GemmArgs ga;
    ga.d[0] = { q_bf, wq_bf, bq, qq_bf, nullptr, 1 };
    ga.d[1] = { k_bf, wk_bf, bk, kk_bf, nullptr, 1 };
    ga.d[2] = { v_bf, wv_bf, bv, vv_bf, nullptr, 1 };
    ga.d[3] = { q_bf, wk_bf, bk, qk_bf, nullptr, 0 };
    ga.d[4] = { q_bf, wv_bf, bv, qv_bf, nullptr, 0 };
    gemm128<<<dim3(S_LEN / 128, 20), 256, 0, stream>>>(ga);

    transpose_bf16<<<dim3(S_LEN / 64, F_DIM / 64), 256, 0, stream>>>(vv_bf, vt_bf);

    gemm_exp<<<dim3(S_LEN / 128, S_LEN / 128), 256, 0, stream>>>(qq_bf, kk_bf, P_bf, lpart);

    gemm_pv<<<dim3(S_LEN / 128, 4 * PSPLIT), 256, 0, stream>>>(P_bf, vt_bf, O_p);

    combine_kernel<<<S_LEN, 128, 0, stream>>>(O_p, lpart, qq_bf, qk_bf, qv_bf, res_bf);

    GemmArgs ga2{};
    ga2.d[0] = { res_bf, wo_bf, bo, nullptr, out, 1 };
    gemm128<<<dim3(S_LEN / 128, 4), 256, 0, stream>>>(ga2);
}